// Round 11
// baseline (121.741 us; speedup 1.0000x reference)
//
#include <hip/hip_runtime.h>

// YOLO loss on MI355X. Inputs: yhat (N,52,52,255) f32, y (N,52,52,255) f32,
// anchors (3,3,2) f32, epoch (ignored: epoch=1 >= EPOCH_PRIOR=0 -> prior=0).
// Outputs: concat [coord(N), class(N), noobj(N), obj(N), prior(1)] f32.
//
// R10 = R5 exactly (persistent 256-thr blocks, BIMG=32, scalar single-phase
// loads, known-good absmax 0.0) + ONE change: all streaming loads are
// NON-TEMPORAL (global_load ... nt, L1-bypass). After eliminating supply-BW,
// occupancy, latency, atomics, and instr-count theories (R3-R9 all flat at
// 78-82us = 4.4TB/s effective), the surviving hypothesis is the per-CU
// L1 line-fill/return path. Data is single-use: nt is semantically ideal.

constexpr int SD      = 52;
constexpr int S2CELLS = SD * SD;        // 2704
constexpr int CH      = 255;            // (5+80)*3
constexpr int CPB     = 16;             // cells per chunk (4 waves x 4 groups)
constexpr int BIMG    = 32;             // blocks per image
constexpr int CHUNKS  = S2CELLS / CPB;  // 169
constexpr float EPSF  = 1e-6f;

__device__ __forceinline__ float flog(float x) {
    return __builtin_amdgcn_logf(x) * 0.69314718055994531f;  // v_log_f32 * ln2
}
__device__ __forceinline__ float frcp(float x) {
    return __builtin_amdgcn_rcpf(x);
}
__device__ __forceinline__ float sel3(int s, float a, float b, float c) {
    return (s == 0) ? a : ((s == 1) ? b : c);   // 2x v_cndmask
}
__device__ __forceinline__ float ntl(const float* p) {
    return __builtin_nontemporal_load(p);       // global_load_dword ... nt
}

__global__ __launch_bounds__(256, 4) void yolo_loss_kernel(
    const float* __restrict__ yhat, const float* __restrict__ yt,
    const float* __restrict__ anchors, float* __restrict__ out, int N)
{
    __shared__ float red[4][4];

    const int tid  = threadIdx.x;
    const int wv   = tid >> 6;
    const int lane = tid & 63;
    const int grp  = lane >> 4;
    const int sub  = lane & 15;
    const int cellLocal = wv * 4 + grp;

    const int n   = blockIdx.x >> 5;          // image index (BIMG = 32)
    const int blk = blockIdx.x & (BIMG - 1);  // block within image

    // anchors[scale_idx=2][b][wh] -> flat offset 12 + 2b
    const float rw0 = frcp(anchors[12]), rh0 = frcp(anchors[13]);
    const float rw1 = frcp(anchors[14]), rh1 = frcp(anchors[15]);
    const float rw2 = frcp(anchors[16]), rh2 = frcp(anchors[17]);
    const float invS = 1.0f / (float)SD;

    float acc_coord = 0.f, acc_class = 0.f, acc_noobj = 0.f, acc_obj = 0.f;

    const size_t imgBase = (size_t)n * S2CELLS * CH;

    for (int c = blk; c < CHUNKS; c += BIMG) {
        const int cellImg = c * CPB + cellLocal;
        const float* __restrict__ A = yhat + imgBase + (size_t)cellImg * CH;
        const float* __restrict__ T = yt   + imgBase + (size_t)cellImg * CH;

        // ---- ALL loads first (addresses independent of any compute) ----
        float av[3][5], tv[3][5];     // box: x,y,w,h,conf (group-broadcast)
        float acv[3][5], tcv[3][5];   // class: lane sub covers c = sub+16k
#pragma unroll
        for (int b = 0; b < 3; b++)
#pragma unroll
            for (int k = 0; k < 5; k++) {
                av[b][k] = ntl(&A[b * 85 + k]);
                tv[b][k] = ntl(&T[b * 85 + k]);
            }
#pragma unroll
        for (int b = 0; b < 3; b++)
#pragma unroll
            for (int k = 0; k < 5; k++) {
                int cc = b * 85 + 5 + sub + k * 16;
                acv[b][k] = ntl(&A[cc]);
                tcv[b][k] = ntl(&T[cc]);
            }

        const int irow = cellImg / SD;
        const int jcol = cellImg - irow * SD;
        const float jf = (float)jcol, if_ = (float)irow;

        // ---- box geometry ----
        float hx1[3], hx2[3], hy1[3], hy2[3], ha[3];
        float tx1[3], tx2[3], ty1[3], ty2[3], ta[3];
#pragma unroll
        for (int b = 0; b < 3; b++) {
            float w = av[b][2], h = av[b][3];
            float cx = (av[b][0] + jf) * invS, cy = (av[b][1] + if_) * invS;
            hx1[b] = cx - 0.5f * w; hx2[b] = cx + 0.5f * w;
            hy1[b] = cy - 0.5f * h; hy2[b] = cy + 0.5f * h;
            ha[b]  = (hx2[b] - hx1[b]) * (hy2[b] - hy1[b]);
        }
#pragma unroll
        for (int b = 0; b < 3; b++) {
            float w = tv[b][2], h = tv[b][3];
            float cx = (tv[b][0] + jf) * invS, cy = (tv[b][1] + if_) * invS;
            tx1[b] = cx - 0.5f * w; tx2[b] = cx + 0.5f * w;
            ty1[b] = cy - 0.5f * h; ty2[b] = cy + 0.5f * h;
            ta[b]  = (tx2[b] - tx1[b]) * (ty2[b] - ty1[b]);
        }

        float iou[3][3];
#pragma unroll
        for (int bp = 0; bp < 3; bp++)
#pragma unroll
            for (int bt = 0; bt < 3; bt++) {
                float wi = fminf(hx2[bp], tx2[bt]) - fmaxf(hx1[bp], tx1[bt]);
                wi = fmaxf(wi, 0.0f);
                float hi = fminf(hy2[bp], ty2[bt]) - fmaxf(hy1[bp], ty1[bt]);
                hi = fmaxf(hi, 0.0f);
                float inter = wi * hi;
                float uni   = ha[bp] + ta[bt] - inter;
                iou[bp][bt] = inter * frcp(uni + EPSF);
            }

        // no-obj (target 0, NO_OBJ_V3)
#pragma unroll
        for (int bp = 0; bp < 3; bp++) {
            float m = fmaxf(fmaxf(iou[bp][0], iou[bp][1]), iou[bp][2]);
            acc_noobj += (m < 0.7f) ? av[bp][4] * av[bp][4] : 0.0f;
        }

        // argmax over pred boxes per target (first-max ties, like jnp.argmax)
        int sel[3];
#pragma unroll
        for (int bt = 0; bt < 3; bt++) {
            int s = 0; float v = iou[0][bt];
            if (iou[1][bt] > v) { v = iou[1][bt]; s = 1; }
            if (iou[2][bt] > v) { s = 2; }
            sel[bt] = s;
        }

        float ho[3];
#pragma unroll
        for (int bt = 0; bt < 3; bt++) {
            int sp = sel[bt];
            float hoo = (tv[bt][4] > 0.0f) ? 1.0f : 0.0f;
            ho[bt] = hoo;
            float phx = sel3(sp, av[0][0], av[1][0], av[2][0]);
            float phy = sel3(sp, av[0][1], av[1][1], av[2][1]);
            float phw = sel3(sp, av[0][2], av[1][2], av[2][2]);
            float phh = sel3(sp, av[0][3], av[1][3], av[2][3]);
            float phc = sel3(sp, av[0][4], av[1][4], av[2][4]);
            float rwp = sel3(sp, rw0, rw1, rw2);
            float rhp = sel3(sp, rh0, rh1, rh2);
            float rwt = (bt == 0) ? rw0 : ((bt == 1) ? rw1 : rw2);
            float rht = (bt == 0) ? rh0 : ((bt == 1) ? rh1 : rh2);
            float dx  = phx - tv[bt][0];
            float dy  = phy - tv[bt][1];
            float dlw = flog(phw * rwp + EPSF) - flog(tv[bt][2] * rwt + EPSF);
            float dlh = flog(phh * rhp + EPSF) - flog(tv[bt][3] * rht + EPSF);
            float csum = dx * dx + dy * dy + dlw * dlw + dlh * dlh;
            acc_coord += csum * hoo * (2.0f - tv[bt][2] * tv[bt][3]);
            float dcf = phc - tv[bt][4];
            acc_obj += dcf * dcf * hoo;
        }

        // class: select VALUES (cndmask), not addresses
#pragma unroll
        for (int bt = 0; bt < 3; bt++) {
            int sp = sel[bt];
            float s = 0.0f;
#pragma unroll
            for (int k = 0; k < 5; k++) {
                float pa = sel3(sp, acv[0][k], acv[1][k], acv[2][k]);
                float d  = pa - tcv[bt][k];
                s += d * d;
            }
            acc_class += s * ho[bt];
        }
    }

    // ---- single final reduction ----
    // coord/noobj/obj replicated x16 within each group -> scale by 1/16 exact.
#pragma unroll
    for (int off = 1; off < 64; off <<= 1) {
        acc_coord += __shfl_xor(acc_coord, off, 64);
        acc_class += __shfl_xor(acc_class, off, 64);
        acc_noobj += __shfl_xor(acc_noobj, off, 64);
        acc_obj   += __shfl_xor(acc_obj,   off, 64);
    }
    if (lane == 0) {
        red[wv][0] = acc_coord; red[wv][1] = acc_class;
        red[wv][2] = acc_noobj; red[wv][3] = acc_obj;
    }
    __syncthreads();
    if (tid < 4) {
        float s = red[0][tid] + red[1][tid] + red[2][tid] + red[3][tid];
        if (tid != 1) s *= 0.0625f;   // un-replicate coord/noobj/obj
        atomicAdd(&out[tid * N + n], s);
    }
}

extern "C" void kernel_launch(void* const* d_in, const int* in_sizes, int n_in,
                              void* d_out, int out_size, void* d_ws, size_t ws_size,
                              hipStream_t stream) {
    const float* yhat = (const float*)d_in[0];
    const float* yv   = (const float*)d_in[1];
    const float* anc  = (const float*)d_in[2];
    float* out = (float*)d_out;

    const int N = in_sizes[0] / (S2CELLS * CH);

    hipMemsetAsync(d_out, 0, (size_t)out_size * sizeof(float), stream);

    dim3 grid(N * BIMG);
    yolo_loss_kernel<<<grid, 256, 0, stream>>>(yhat, yv, anc, out, N);
}